// Round 12
// baseline (830.581 us; speedup 1.0000x reference)
//
#include <hip/hip_runtime.h>
#include <hip/hip_bf16.h>

typedef short short8 __attribute__((ext_vector_type(8)));
typedef float f32x4 __attribute__((ext_vector_type(4)));

#define T_ 512
#define B_ 1024
#define D_ 128
#define H_ 64
#define A_ 18
#define TB_ (T_*B_)

// ws layout (ushort units): [x_actor | x_critic | bf16 weights]
#define XELEMS (TB_*H_)          // 33554432 per branch
#define WBASE  (2*XELEMS)
#define WBR    38912             // per-branch weight elems
#define W1OFF  0
#define W2OFF  8192
#define WIHOFF 12288
#define WHHOFF 24576
#define WHDOFF 36864

// out layout (floats): logits | values | actor_state | critic_state
#define LOGN  (TB_*A_)           // 9437184
#define VOFF_ LOGN
#define SOFF_ (LOGN + TB_)       // 9961472

#define S1_ (-1.4426950408889634f)   // -log2(e)   (r,z gates)
#define S2_ (-2.885390081777927f)    // -2*log2(e) (n gate)

__device__ __forceinline__ ushort f2bf(float f) {
  __hip_bfloat16 h = __float2bfloat16(f);
  return __builtin_bit_cast(ushort, h);
}
__device__ __forceinline__ uint cvt_pk_bf16(float lo, float hi) {
  uint r;
  asm("v_cvt_pk_bf16_f32 %0, %1, %2" : "=v"(r) : "v"(lo), "v"(hi));
  return r;
}
__device__ __forceinline__ ushort cvt1_bf16(float v) {
  return (ushort)(cvt_pk_bf16(v, v) & 0xffffu);
}
__device__ __forceinline__ f32x4 mfma16(short8 a, short8 b, f32x4 c) {
  return __builtin_amdgcn_mfma_f32_16x16x32_bf16(a, b, c, 0, 0, 0);
}

__global__ __launch_bounds__(256) void prep_kernel(
    const float* aW1, const float* aW2, const float* aWih, const float* aWhh, const float* aWl,
    const float* cW1, const float* cW2, const float* cWih, const float* cWhh, const float* cWv,
    ushort* wts) {
  int idx = blockIdx.x * 256 + threadIdx.x;
  if (idx >= 2*WBR) return;
  int br = idx / WBR, off = idx % WBR;
  float v;
  if      (off < W2OFF)  v = (br ? cW1  : aW1 )[off];
  else if (off < WIHOFF) v = (br ? cW2  : aW2 )[off - W2OFF];
  else if (off < WHHOFF) {
    int rel = off - WIHOFF;
    v = (br ? cWih : aWih)[rel];
    v *= (rel < 128*H_) ? S1_ : S2_;      // fold gate logistic scales
  }
  else if (off < WHDOFF) {
    int rel = off - WHHOFF;
    v = (br ? cWhh : aWhh)[rel];
    v *= (rel < 128*H_) ? S1_ : S2_;
  }
  else {
    int t = off - WHDOFF;
    if (br == 0) v = (t < A_*H_) ? aWl[t] : 0.f;
    else         v = (t < H_)    ? cWv[t] : 0.f;
  }
  wts[WBASE + idx] = f2bf(v);
}

// ================= phase 1: MLP (ablation-instrumented, 4 named variants) =============
// VAR 0: real (R9 structure).  VAR 1: weights from LDS.  VAR 2: no obs loads (synth).
// VAR 3: stream floor (obs load -> cvt -> coalesced store; no MFMA/LDS).
// wlds layout (VAR 1): [W1A 8192 | W1C 8192 | W2A 4096 | W2C 4096], 16B chunks swizzled
// within each row: chunk' = (chunk&~7) | ((chunk&7) ^ (row&7)).
template<int VAR>
__device__ __forceinline__ void mlp_impl(
    const float* __restrict__ obs, const ushort* __restrict__ wts,
    const float* __restrict__ ab1, const float* __restrict__ ab2,
    const float* __restrict__ cb1, const float* __restrict__ cb2,
    ushort* __restrict__ xout,
    ushort (*htA)[16 * H_], ushort (*htC)[16 * H_], ushort* wlds) {
  const int tid = threadIdx.x;
  const int l = tid & 63, w = tid >> 6;
  const int lr = l & 15, lg = l >> 4;
  const int key = lr & 7;
  const long r0 = (long)blockIdx.x * 64;
  const long row = r0 + w * 16 + lr;
  const f32x4 fzero = {0.f, 0.f, 0.f, 0.f};
  const ushort* wbA = wts + WBASE;
  const ushort* wbC = wts + WBASE + WBR;

  if constexpr (VAR == 1) {
    // stage all four weight matrices into LDS, chunk-swizzled
    #pragma unroll
    for (int i = 0; i < 12; ++i) {
      int c = tid + i * 256;              // 3072 chunks of 8 elems
      int seg = (c < 1024) ? 0 : (c < 2048) ? 1 : (c < 2560) ? 2 : 3;
      int cbase = (seg == 0) ? 0 : (seg == 1) ? 1024 : (seg == 2) ? 2048 : 2560;
      int off = (c - cbase) * 8;
      int L = (seg < 2) ? 128 : 64;
      int segdst = (seg == 0) ? 0 : (seg == 1) ? 8192 : (seg == 2) ? 16384 : 20480;
      const ushort* src = (seg == 0) ? wbA + W1OFF + off :
                          (seg == 1) ? wbC + W1OFF + off :
                          (seg == 2) ? wbA + W2OFF + off : wbC + W2OFF + off;
      int n = off / L, ci = (off % L) / 8;
      int cis = (ci & ~7) | ((ci & 7) ^ (n & 7));
      *(uint4*)(wlds + segdst + n * L + cis * 8) = *(const uint4*)src;
    }
    __syncthreads();
  }

  auto getW1 = [&](int br, int n, int ks) -> short8 {
    if constexpr (VAR == 1) {
      int ci = ks * 4 + lg;
      int cis = (ci & 8) | ((ci & 7) ^ (n & 7));
      return *(const short8*)(wlds + br * 8192 + n * D_ + cis * 8);
    } else {
      return *(const short8*)((br ? wbC : wbA) + W1OFF + n * D_ + ks * 32 + lg * 8);
    }
  };
  auto getW2 = [&](int br, int n, int ks) -> short8 {
    if constexpr (VAR == 1) {
      int ci = ks * 4 + lg;                // 0..7
      int cis = ci ^ (n & 7);
      return *(const short8*)(wlds + 16384 + br * 4096 + n * H_ + cis * 8);
    } else {
      return *(const short8*)((br ? wbC : wbA) + W2OFF + n * H_ + ks * 32 + lg * 8);
    }
  };

  // obs A-fragments
  short8 af[4];
  if constexpr (VAR == 2) {
    uint s0 = 0x3E003E00u ^ ((uint)tid * 0x01010001u & 0x00FF00FFu);
    #pragma unroll
    for (int ks = 0; ks < 4; ++ks) {
      uint4 u;
      u.x = s0 + (uint)ks;
      u.y = s0 ^ ((uint)ks * 0x00010001u);
      u.z = s0 + 0x00020002u;
      u.w = s0 ^ 0x00030001u;
      af[ks] = __builtin_bit_cast(short8, u);
    }
  } else {
    const float* op = obs + row * D_;
    #pragma unroll
    for (int ks = 0; ks < 4; ++ks) {
      float4 f0 = *(const float4*)(op + ks * 32 + lg * 8);
      float4 f1 = *(const float4*)(op + ks * 32 + lg * 8 + 4);
      uint4 u;
      u.x = cvt_pk_bf16(f0.x, f0.y);
      u.y = cvt_pk_bf16(f0.z, f0.w);
      u.z = cvt_pk_bf16(f1.x, f1.y);
      u.w = cvt_pk_bf16(f1.z, f1.w);
      af[ks] = __builtin_bit_cast(short8, u);
    }
  }

  if constexpr (VAR == 3) {
    // stream floor: coalesced stores of converted obs, same volume as real copy-out
    ushort* dpA = xout + (size_t)(r0 + w * 16) * H_;
    ushort* dpC = xout + (size_t)XELEMS + (size_t)(r0 + w * 16) * H_;
    *(uint4*)(dpA + l * 16)     = __builtin_bit_cast(uint4, af[0]);
    *(uint4*)(dpA + l * 16 + 8) = __builtin_bit_cast(uint4, af[1]);
    *(uint4*)(dpC + l * 16)     = __builtin_bit_cast(uint4, af[2]);
    *(uint4*)(dpC + l * 16 + 8) = __builtin_bit_cast(uint4, af[3]);
    return;
  }

  // ---- layer 1, both branches interleaved
  f32x4 aA[4], aC[4];
  #pragma unroll
  for (int nt = 0; nt < 4; ++nt) { aA[nt] = fzero; aC[nt] = fzero; }
  #pragma unroll
  for (int ks = 0; ks < 4; ++ks) {
    #pragma unroll
    for (int nt = 0; nt < 4; ++nt) {
      int n = nt * 16 + lr;
      aA[nt] = mfma16(af[ks], getW1(0, n, ks), aA[nt]);
      aC[nt] = mfma16(af[ks], getW1(1, n, ks), aC[nt]);
    }
  }
  #pragma unroll
  for (int nt = 0; nt < 4; ++nt) {
    int coln = nt * 16 + lr;
    float bA_ = ab1[coln], bC_ = cb1[coln];
    #pragma unroll
    for (int j = 0; j < 4; ++j) {
      int rw = lg * 4 + j;
      int idx = rw * H_ + ((((coln >> 3) ^ (rw & 7))) << 3) + (coln & 7);
      htA[w][idx] = cvt1_bf16(fmaxf(aA[nt][j] + bA_, 0.f));
      htC[w][idx] = cvt1_bf16(fmaxf(aC[nt][j] + bC_, 0.f));
    }
  }
  // ---- layer 2, interleaved (wave-local ds round-trip)
  short8 a2A[2], a2C[2];
  #pragma unroll
  for (int ks = 0; ks < 2; ++ks) {
    int c = ks * 4 + lg;
    a2A[ks] = *(const short8*)(&htA[w][lr * H_ + ((c ^ key) << 3)]);
    a2C[ks] = *(const short8*)(&htC[w][lr * H_ + ((c ^ key) << 3)]);
  }
  f32x4 cA[4], cC[4];
  #pragma unroll
  for (int nt = 0; nt < 4; ++nt) { cA[nt] = fzero; cC[nt] = fzero; }
  #pragma unroll
  for (int ks = 0; ks < 2; ++ks) {
    #pragma unroll
    for (int nt = 0; nt < 4; ++nt) {
      int n = nt * 16 + lr;
      cA[nt] = mfma16(a2A[ks], getW2(0, n, ks), cA[nt]);
      cC[nt] = mfma16(a2C[ks], getW2(1, n, ks), cC[nt]);
    }
  }
  #pragma unroll
  for (int nt = 0; nt < 4; ++nt) {
    int coln = nt * 16 + lr;
    float bA_ = ab2[coln], bC_ = cb2[coln];
    #pragma unroll
    for (int j = 0; j < 4; ++j) {
      int rw = lg * 4 + j;
      int idx = rw * H_ + ((((coln >> 3) ^ (rw & 7))) << 3) + (coln & 7);
      htA[w][idx] = cvt1_bf16(fmaxf(cA[nt][j] + bA_, 0.f));
      htC[w][idx] = cvt1_bf16(fmaxf(cC[nt][j] + bC_, 0.f));
    }
  }
  // de-swizzling copy-out, both branches: PLAIN row-major x
  {
    ushort* dpA = xout + (size_t)(r0 + w * 16) * H_;
    ushort* dpC = xout + (size_t)XELEMS + (size_t)(r0 + w * 16) * H_;
    #pragma unroll
    for (int i = 0; i < 2; ++i) {
      int id = l + i * 64;          // 128 chunks of 16B
      int rr = id >> 3, cc = id & 7;
      uint4 vA = *(const uint4*)(&htA[w][rr * H_ + ((cc ^ (rr & 7)) << 3)]);
      *(uint4*)(dpA + rr * H_ + (cc << 3)) = vA;
      uint4 vC = *(const uint4*)(&htC[w][rr * H_ + ((cc ^ (rr & 7)) << 3)]);
      *(uint4*)(dpC + rr * H_ + (cc << 3)) = vC;
    }
  }
}

#define MLP_ARGS const float* __restrict__ obs, const ushort* __restrict__ wts, \
    const float* __restrict__ ab1, const float* __restrict__ ab2, \
    const float* __restrict__ cb1, const float* __restrict__ cb2, \
    ushort* __restrict__ xout
__global__ __launch_bounds__(256) void mlp_real(MLP_ARGS) {
  __shared__ __align__(16) ushort htA[4][16 * H_], htC[4][16 * H_];
  mlp_impl<0>(obs, wts, ab1, ab2, cb1, cb2, xout, htA, htC, nullptr);
}
__global__ __launch_bounds__(256) void mlp_v1(MLP_ARGS) {
  __shared__ __align__(16) ushort htA[4][16 * H_], htC[4][16 * H_];
  __shared__ __align__(16) ushort wlds[24576];
  mlp_impl<1>(obs, wts, ab1, ab2, cb1, cb2, xout, htA, htC, wlds);
}
__global__ __launch_bounds__(256) void mlp_v2(MLP_ARGS) {
  __shared__ __align__(16) ushort htA[4][16 * H_], htC[4][16 * H_];
  mlp_impl<2>(obs, wts, ab1, ab2, cb1, cb2, xout, htA, htC, nullptr);
}
__global__ __launch_bounds__(256) void mlp_v3(MLP_ARGS) {
  mlp_impl<3>(obs, wts, ab1, ab2, cb1, cb2, xout, nullptr, nullptr, nullptr);
}

// ---------------- phase 2: GRU scan, short-chain schedule (R8 structure) --------------
__global__ __launch_bounds__(256, 1) void scan_kernel(
    const ushort* __restrict__ wts,     // ws + WBASE region
    const ushort* __restrict__ xin,     // ws x region (load-only view)
    ushort* __restrict__ hist,          // ws x region (store-only view; t-disjoint)
    const float* __restrict__ dones,
    const float* __restrict__ astate, const float* __restrict__ cstate,
    const float* __restrict__ abih, const float* __restrict__ abhh,
    const float* __restrict__ cbih, const float* __restrict__ cbhh,
    float* __restrict__ out) {
  __shared__ __align__(16) ushort hbuf[2][16 * H_];  // h^T tiles, 16B-unit swizzled
  __shared__ __align__(8)  ushort dl16[T_ * 16];     // done flags, 16KB
  const int tid = threadIdx.x;
  const int l = tid & 63, w = tid >> 6;
  const int lr = l & 15, lg = l >> 4;
  const int grp = blockIdx.x & 1;
  const int b0 = (blockIdx.x >> 1) * 16;

  const ushort* wb = wts + grp * WBR;
  const ushort* xp = xin + (size_t)grp * XELEMS;
  ushort* hp = hist + (size_t)grp * XELEMS;
  const float* bihp = grp ? cbih : abih;
  const float* bhhp = grp ? cbhh : abhh;
  const float* st   = grp ? cstate : astate;

  // dones -> LDS flags
  #pragma unroll
  for (int i = 0; i < 8; ++i) {
    int s = tid + i * 256;
    int t = s >> 2, p = s & 3;
    float4 v = *(const float4*)(dones + (size_t)t * B_ + b0 + p * 4);
    uint lo = (v.x != 0.f ? 1u : 0u) | ((v.y != 0.f ? 1u : 0u) << 16);
    uint hi = (v.z != 0.f ? 1u : 0u) | ((v.w != 0.f ? 1u : 0u) << 16);
    *(uint2*)(&dl16[t * 16 + p * 4]) = uint2{lo, hi};
  }

  short8 ihW[3][2], hhW[3][2];
  #pragma unroll
  for (int g = 0; g < 3; ++g) {
    int n = g * 64 + w * 16 + lr;
    #pragma unroll
    for (int ks = 0; ks < 2; ++ks) {
      ihW[g][ks] = *(const short8*)(wb + WIHOFF + n * H_ + ks * 32 + lg * 8);
      hhW[g][ks] = *(const short8*)(wb + WHHOFF + n * H_ + ks * 32 + lg * 8);
    }
  }

  const int o4 = w * 16 + lg * 4;
  f32x4 bs0, bs1, binv, bhnv;
  {
    float4 a0 = *(const float4*)(bihp + o4),       h0v = *(const float4*)(bhhp + o4);
    float4 a1 = *(const float4*)(bihp + 64 + o4),  h1v = *(const float4*)(bhhp + 64 + o4);
    float4 a2 = *(const float4*)(bihp + 128 + o4), h2v = *(const float4*)(bhhp + 128 + o4);
    bs0[0]=S1_*(a0.x+h0v.x); bs0[1]=S1_*(a0.y+h0v.y); bs0[2]=S1_*(a0.z+h0v.z); bs0[3]=S1_*(a0.w+h0v.w);
    bs1[0]=S1_*(a1.x+h1v.x); bs1[1]=S1_*(a1.y+h1v.y); bs1[2]=S1_*(a1.z+h1v.z); bs1[3]=S1_*(a1.w+h1v.w);
    binv[0]=S2_*a2.x; binv[1]=S2_*a2.y; binv[2]=S2_*a2.z; binv[3]=S2_*a2.w;
    bhnv[0]=S2_*h2v.x; bhnv[1]=S2_*h2v.y; bhnv[2]=S2_*h2v.z; bhnv[3]=S2_*h2v.w;
  }

  const int myW = lr * H_ + (((w * 2 + (lg >> 1)) ^ (lr & 7)) << 3) + (lg & 1) * 4;
  const int rdA = lr * H_ + (((0 + lg) ^ (lr & 7)) << 3);
  const int rdB = lr * H_ + (((4 + lg) ^ (lr & 7)) << 3);

  float h_old[4];
  {
    float4 h0v = *(const float4*)(st + (size_t)(b0 + lr) * H_ + o4);
    bool rs0 = (dones[b0 + lr] != 0.f);
    h_old[0] = rs0 ? 0.f : h0v.x; h_old[1] = rs0 ? 0.f : h0v.y;
    h_old[2] = rs0 ? 0.f : h0v.z; h_old[3] = rs0 ? 0.f : h0v.w;
    uint2 hv;
    hv.x = cvt_pk_bf16(h_old[0], h_old[1]);
    hv.y = cvt_pk_bf16(h_old[2], h_old[3]);
    *(uint2*)(&hbuf[0][myW]) = hv;
  }

  __syncthreads();

  auto loadx = [&](int t, short8 (&f)[2]) {
    const ushort* p = xp + ((size_t)t * B_ + b0 + lr) * H_;
    f[0] = *(const short8*)(p + lg * 8);
    f[1] = *(const short8*)(p + 32 + lg * 8);
  };

  short8 buf0[2], buf1[2], buf2[2], buf3[2];
  loadx(0, buf0); loadx(1, buf1); loadx(2, buf2); loadx(3, buf3);

  // pre[g] = bias + ih·x for the step about to run (x-side, h-independent)
  f32x4 preA[3], preB[3];
  auto cpre = [&](short8 (&xb)[2], f32x4 (&pre)[3]) {
    pre[0] = bs0;  pre[1] = bs1;  pre[2] = binv;
    pre[0] = mfma16(ihW[0][0], xb[0], pre[0]); pre[0] = mfma16(ihW[0][1], xb[1], pre[0]);
    pre[1] = mfma16(ihW[1][0], xb[0], pre[1]); pre[1] = mfma16(ihW[1][1], xb[1], pre[1]);
    pre[2] = mfma16(ihW[2][0], xb[0], pre[2]); pre[2] = mfma16(ihW[2][1], xb[1], pre[2]);
  };
  cpre(buf0, preA);

  int cur = 0;

  auto dostep = [&](int t, short8 (&xcur)[2], short8 (&xnext)[2],
                    f32x4 (&preU)[3], f32x4 (&preN)[3]) {
    short8 hf0 = *(const short8*)(&hbuf[cur][rdA]);
    short8 hf1 = *(const short8*)(&hbuf[cur][rdB]);
    int tn = t + 1;
    ushort dn = dl16[((tn < T_) ? tn : 0) * 16 + lr];
    bool rs = (tn < T_) && (dn != 0);

    // critical path: 2 chained hh-MFMAs per gate (C = bias + ih·x, precomputed)
    f32x4 S0 = preU[0], S1 = preU[1], Gh = bhnv;
    S0 = mfma16(hhW[0][0], hf0, S0); S0 = mfma16(hhW[0][1], hf1, S0);
    S1 = mfma16(hhW[1][0], hf0, S1); S1 = mfma16(hhW[1][1], hf1, S1);
    Gh = mfma16(hhW[2][0], hf0, Gh); Gh = mfma16(hhW[2][1], hf1, Gh);

    // latency shadow: x-side MFMAs for t+1 and the t+4 prefetch
    cpre(xnext, preN);
    int tp = (t + 4 < T_) ? t + 4 : T_ - 1;
    loadx(tp, xcur);

    float hn[4];
    #pragma unroll
    for (int j = 0; j < 4; ++j) {
      float rr = __builtin_amdgcn_rcpf(1.f + __builtin_amdgcn_exp2f(S0[j]));
      float zz = __builtin_amdgcn_rcpf(1.f + __builtin_amdgcn_exp2f(S1[j]));
      float sn = fmaf(rr, Gh[j], preU[2][j]);
      float qq = __builtin_amdgcn_rcpf(1.f + __builtin_amdgcn_exp2f(sn));
      float nn = fmaf(2.f, qq, -1.f);
      hn[j] = fmaf(zz, h_old[j] - nn, nn);
    }
    uint2 hv;
    hv.x = cvt_pk_bf16(hn[0], hn[1]);
    hv.y = cvt_pk_bf16(hn[2], hn[3]);
    *(uint2*)(hp + ((size_t)t * B_ + b0 + lr) * H_ + o4) = hv;   // history (pre-reset)
    uint2 hz;
    hz.x = rs ? 0u : hv.x;
    hz.y = rs ? 0u : hv.y;
    h_old[0] = rs ? 0.f : hn[0]; h_old[1] = rs ? 0.f : hn[1];
    h_old[2] = rs ? 0.f : hn[2]; h_old[3] = rs ? 0.f : hn[3];
    int nxt = cur ^ 1;
    *(uint2*)(&hbuf[nxt][myW]) = hz;
    asm volatile("s_waitcnt lgkmcnt(0)" ::: "memory");
    __builtin_amdgcn_s_barrier();
    cur = nxt;
  };

  for (int it = 0; it < T_ / 4; ++it) {
    dostep(4 * it,     buf0, buf1, preA, preB);
    dostep(4 * it + 1, buf1, buf2, preB, preA);
    dostep(4 * it + 2, buf2, buf3, preA, preB);
    dostep(4 * it + 3, buf3, buf0, preB, preA);
  }

  // final states (fp32, post step 511; no reset applied on last step)
  float4 fs = {h_old[0], h_old[1], h_old[2], h_old[3]};
  *(float4*)(out + SOFF_ + (size_t)grp * (B_ * H_) + (size_t)(b0 + lr) * H_ + o4) = fs;
}

// ---------------- phase 3: heads (logits + values), LDS-staged coalesced stores -------
__global__ __launch_bounds__(256) void head_kernel(
    const ushort* __restrict__ ws,
    const float* __restrict__ abl, const float* __restrict__ cbv,
    float* __restrict__ out) {
  __shared__ float ltile[4][16 * A_];
  const int tid = threadIdx.x;
  const int l = tid & 63, w = tid >> 6;
  const int lr = l & 15, lg = l >> 4;
  const long r0 = (long)blockIdx.x * 64 + w * 16;
  const f32x4 fzero = {0.f, 0.f, 0.f, 0.f};

  const ushort* hA = ws + r0 * H_;
  const ushort* hC = ws + XELEMS + r0 * H_;
  short8 aA[2], aC[2];
  #pragma unroll
  for (int ks = 0; ks < 2; ++ks) {
    aA[ks] = *(const short8*)(hA + lr * H_ + ks * 32 + lg * 8);
    aC[ks] = *(const short8*)(hC + lr * H_ + ks * 32 + lg * 8);
  }
  const ushort* wbA = ws + WBASE + WHDOFF;
  const ushort* wbC = ws + WBASE + WBR + WHDOFF;
  f32x4 acc[2];
  acc[0] = fzero; acc[1] = fzero;
  #pragma unroll
  for (int nt = 0; nt < 2; ++nt) {
    int n = nt * 16 + lr;
    #pragma unroll
    for (int ks = 0; ks < 2; ++ks) {
      short8 b = *(const short8*)(wbA + n * H_ + ks * 32 + lg * 8);
      acc[nt] = mfma16(aA[ks], b, acc[nt]);
    }
  }
  f32x4 vacc = fzero;
  {
    int n = lr;
    #pragma unroll
    for (int ks = 0; ks < 2; ++ks) {
      short8 b = *(const short8*)(wbC + n * H_ + ks * 32 + lg * 8);
      vacc = mfma16(aC[ks], b, vacc);
    }
  }
  #pragma unroll
  for (int nt = 0; nt < 2; ++nt) {
    int n = nt * 16 + lr;
    if (n < A_) {
      float bias = abl[n];
      #pragma unroll
      for (int j = 0; j < 4; ++j)
        ltile[w][(lg * 4 + j) * A_ + n] = acc[nt][j] + bias;
    }
  }
  asm volatile("s_waitcnt lgkmcnt(0)" ::: "memory");
  #pragma unroll
  for (int i = 0; i < 5; ++i) {
    int idx = l + i * 64;
    if (idx < 16 * A_)
      out[r0 * A_ + idx] = ltile[w][idx];
  }
  if (lr == 0) {
    float bias = cbv[0];
    #pragma unroll
    for (int j = 0; j < 4; ++j)
      out[VOFF_ + r0 + lg * 4 + j] = vacc[j] + bias;
  }
}

extern "C" void kernel_launch(void* const* d_in, const int* in_sizes, int n_in,
                              void* d_out, int out_size, void* d_ws, size_t ws_size,
                              hipStream_t stream) {
  const float* obs    = (const float*)d_in[0];
  const float* dones  = (const float*)d_in[1];
  const float* astate = (const float*)d_in[2];
  const float* cstate = (const float*)d_in[3];
  const float* aW1  = (const float*)d_in[4];
  const float* ab1  = (const float*)d_in[5];
  const float* aW2  = (const float*)d_in[6];
  const float* ab2  = (const float*)d_in[7];
  const float* aWih = (const float*)d_in[8];
  const float* aWhh = (const float*)d_in[9];
  const float* abih = (const float*)d_in[10];
  const float* abhh = (const float*)d_in[11];
  const float* aWl  = (const float*)d_in[12];
  const float* abl  = (const float*)d_in[13];
  const float* cW1  = (const float*)d_in[14];
  const float* cb1  = (const float*)d_in[15];
  const float* cW2  = (const float*)d_in[16];
  const float* cb2  = (const float*)d_in[17];
  const float* cWih = (const float*)d_in[18];
  const float* cWhh = (const float*)d_in[19];
  const float* cbih = (const float*)d_in[20];
  const float* cbhh = (const float*)d_in[21];
  const float* cWv  = (const float*)d_in[22];
  const float* cbv  = (const float*)d_in[23];
  ushort* ws = (ushort*)d_ws;
  float* out = (float*)d_out;

  const size_t need = ((size_t)2 * XELEMS + 2 * WBR) * 2;
  if (ws_size < need) {
    hipMemsetAsync(d_out, 0x7F, 16, stream);
    return;
  }

  hipLaunchKernelGGL(prep_kernel, dim3(304), dim3(256), 0, stream,
                     aW1, aW2, aWih, aWhh, aWl, cW1, cW2, cWih, cWhh, cWv, ws);
  // ---- ablation probes (full-size; x region fully overwritten by mlp_real after) ----
  hipLaunchKernelGGL(mlp_v1, dim3(TB_ / 64), dim3(256), 0, stream,
                     obs, ws, ab1, ab2, cb1, cb2, ws);
  hipLaunchKernelGGL(mlp_v2, dim3(TB_ / 64), dim3(256), 0, stream,
                     obs, ws, ab1, ab2, cb1, cb2, ws);
  hipLaunchKernelGGL(mlp_v3, dim3(TB_ / 64), dim3(256), 0, stream,
                     obs, ws, ab1, ab2, cb1, cb2, ws);
  // ---- real path ----
  hipLaunchKernelGGL(mlp_real, dim3(TB_ / 64), dim3(256), 0, stream,
                     obs, ws, ab1, ab2, cb1, cb2, ws);
  hipLaunchKernelGGL(scan_kernel, dim3(128), dim3(256), 0, stream,
                     ws + WBASE, ws, ws, dones, astate, cstate,
                     abih, abhh, cbih, cbhh, out);
  hipLaunchKernelGGL(head_kernel, dim3(TB_ / 64), dim3(256), 0, stream,
                     ws, abl, cbv, out);
}

// Round 13
// 342.979 us; speedup vs baseline: 2.4217x; 2.4217x over previous
//
#include <hip/hip_runtime.h>
#include <hip/hip_bf16.h>

typedef short short8 __attribute__((ext_vector_type(8)));
typedef float f32x4 __attribute__((ext_vector_type(4)));

#define T_ 512
#define B_ 1024
#define D_ 128
#define H_ 64
#define A_ 18
#define TB_ (T_*B_)

// ws layout (ushort units): [x_actor | x_critic | bf16 weights]
#define XELEMS (TB_*H_)          // 33554432 per branch
#define WBASE  (2*XELEMS)
#define WBR    38912             // per-branch weight elems
#define W1OFF  0
#define W2OFF  8192
#define WIHOFF 12288
#define WHHOFF 24576
#define WHDOFF 36864

// out layout (floats): logits | values | actor_state | critic_state
#define LOGN  (TB_*A_)           // 9437184
#define VOFF_ LOGN
#define SOFF_ (LOGN + TB_)       // 9961472

#define S1_ (-1.4426950408889634f)   // -log2(e)   (r,z gates)
#define S2_ (-2.885390081777927f)    // -2*log2(e) (n gate)

__device__ __forceinline__ ushort f2bf(float f) {
  __hip_bfloat16 h = __float2bfloat16(f);
  return __builtin_bit_cast(ushort, h);
}
__device__ __forceinline__ uint cvt_pk_bf16(float lo, float hi) {
  uint r;
  asm("v_cvt_pk_bf16_f32 %0, %1, %2" : "=v"(r) : "v"(lo), "v"(hi));
  return r;
}
__device__ __forceinline__ ushort cvt1_bf16(float v) {
  return (ushort)(cvt_pk_bf16(v, v) & 0xffffu);
}
__device__ __forceinline__ f32x4 mfma16(short8 a, short8 b, f32x4 c) {
  return __builtin_amdgcn_mfma_f32_16x16x32_bf16(a, b, c, 0, 0, 0);
}

__global__ __launch_bounds__(256) void prep_kernel(
    const float* aW1, const float* aW2, const float* aWih, const float* aWhh, const float* aWl,
    const float* cW1, const float* cW2, const float* cWih, const float* cWhh, const float* cWv,
    ushort* wts) {
  int idx = blockIdx.x * 256 + threadIdx.x;
  if (idx >= 2*WBR) return;
  int br = idx / WBR, off = idx % WBR;
  float v;
  if      (off < W2OFF)  v = (br ? cW1  : aW1 )[off];
  else if (off < WIHOFF) v = (br ? cW2  : aW2 )[off - W2OFF];
  else if (off < WHHOFF) {
    int rel = off - WIHOFF;
    v = (br ? cWih : aWih)[rel];
    v *= (rel < 128*H_) ? S1_ : S2_;      // fold gate logistic scales
  }
  else if (off < WHDOFF) {
    int rel = off - WHHOFF;
    v = (br ? cWhh : aWhh)[rel];
    v *= (rel < 128*H_) ? S1_ : S2_;
  }
  else {
    int t = off - WHDOFF;
    if (br == 0) v = (t < A_*H_) ? aWl[t] : 0.f;
    else         v = (t < H_)    ? cWv[t] : 0.f;
  }
  wts[WBASE + idx] = f2bf(v);
}

// ---- phase 1: MLP, persistent blocks (4 tiles), weights staged in LDS ----------------
// Key: the ONLY vmcnt traffic is 8 obs loads/tile (issued one compute ahead) + stores.
// All weight reads are LDS (lgkm domain) -> no in-order-queue pollution behind HBM obs.
__global__ __launch_bounds__(256) void mlp_kernel(
    const float* __restrict__ obs, const ushort* __restrict__ wts,
    const float* __restrict__ ab1, const float* __restrict__ ab2,
    const float* __restrict__ cb1, const float* __restrict__ cb2,
    ushort* __restrict__ xout) {
  __shared__ __align__(16) ushort htA[4][16 * H_], htC[4][16 * H_];  // per-wave bounce
  __shared__ __align__(16) ushort wlds[24576];                      // 48KB weights
  const int tid = threadIdx.x;
  const int l = tid & 63, w = tid >> 6;
  const int lr = l & 15, lg = l >> 4;
  const int key = lr & 7;
  const long base = (long)blockIdx.x * 256;     // 4 tiles x 64 rows
  const ushort* wbA = wts + WBASE;
  const ushort* wbC = wts + WBASE + WBR;

  // biases for this lane's output cols (hoisted; off the per-tile path)
  const int colq[2] = {lr, 16 + lr};            // pattern repeats per 32
  float b1A[4], b1C[4], b2A[4], b2C[4];
  #pragma unroll
  for (int nt = 0; nt < 4; ++nt) {
    int coln = nt * 16 + lr;
    b1A[nt] = ab1[coln]; b1C[nt] = cb1[coln];
    b2A[nt] = ab2[coln]; b2C[nt] = cb2[coln];
  }
  (void)colq;

  // ---- stage all four weight matrices into LDS, 16B-chunk-swizzled -------------------
  // layout: [W1A 8192 | W1C 8192 | W2A 4096 | W2C 4096] (elems); within row n of
  // length L chunks, chunk' = (ci&~7) | ((ci&7) ^ (n&7)).
  #pragma unroll
  for (int i = 0; i < 12; ++i) {
    int c = tid + i * 256;              // 3072 chunks of 8 elems
    int seg = (c < 1024) ? 0 : (c < 2048) ? 1 : (c < 2560) ? 2 : 3;
    int cbase = (seg == 0) ? 0 : (seg == 1) ? 1024 : (seg == 2) ? 2048 : 2560;
    int off = (c - cbase) * 8;
    int L = (seg < 2) ? 128 : 64;
    int segdst = (seg == 0) ? 0 : (seg == 1) ? 8192 : (seg == 2) ? 16384 : 20480;
    const ushort* src = (seg == 0) ? wbA + W1OFF + off :
                        (seg == 1) ? wbC + W1OFF + off :
                        (seg == 2) ? wbA + W2OFF + off : wbC + W2OFF + off;
    int n = off / L, ci = (off % L) / 8;
    int cis = (ci & ~7) | ((ci & 7) ^ (n & 7));
    *(uint4*)(wlds + segdst + n * L + cis * 8) = *(const uint4*)src;
  }
  __syncthreads();

  auto getW1 = [&](int br, int n, int ks) -> short8 {
    int ci = ks * 4 + lg;
    int cis = (ci & 8) | ((ci & 7) ^ (n & 7));
    return *(const short8*)(wlds + br * 8192 + n * D_ + cis * 8);
  };
  auto getW2 = [&](int br, int n, int ks) -> short8 {
    int ci = ks * 4 + lg;                // 0..7
    int cis = ci ^ (n & 7);
    return *(const short8*)(wlds + 16384 + br * 4096 + n * H_ + cis * 8);
  };

  auto ldobs = [&](int s, float4 (&buf)[8]) {
    const float* op = obs + (base + s * 64 + (long)w * 16 + lr) * D_;
    #pragma unroll
    for (int ks = 0; ks < 4; ++ks) {
      buf[2 * ks]     = *(const float4*)(op + ks * 32 + lg * 8);
      buf[2 * ks + 1] = *(const float4*)(op + ks * 32 + lg * 8 + 4);
    }
  };

  auto compute = [&](int s, float4 (&buf)[8]) {
    short8 af[4];
    #pragma unroll
    for (int ks = 0; ks < 4; ++ks) {
      uint4 u;
      u.x = cvt_pk_bf16(buf[2 * ks].x, buf[2 * ks].y);
      u.y = cvt_pk_bf16(buf[2 * ks].z, buf[2 * ks].w);
      u.z = cvt_pk_bf16(buf[2 * ks + 1].x, buf[2 * ks + 1].y);
      u.w = cvt_pk_bf16(buf[2 * ks + 1].z, buf[2 * ks + 1].w);
      af[ks] = __builtin_bit_cast(short8, u);
    }
    // layer 1, both branches interleaved; bias in C-init
    f32x4 aA[4], aC[4];
    #pragma unroll
    for (int nt = 0; nt < 4; ++nt) {
      aA[nt] = f32x4{b1A[nt], b1A[nt], b1A[nt], b1A[nt]};
      aC[nt] = f32x4{b1C[nt], b1C[nt], b1C[nt], b1C[nt]};
    }
    #pragma unroll
    for (int ks = 0; ks < 4; ++ks) {
      #pragma unroll
      for (int nt = 0; nt < 4; ++nt) {
        int n = nt * 16 + lr;
        aA[nt] = mfma16(af[ks], getW1(0, n, ks), aA[nt]);
        aC[nt] = mfma16(af[ks], getW1(1, n, ks), aC[nt]);
      }
    }
    #pragma unroll
    for (int nt = 0; nt < 4; ++nt) {
      int coln = nt * 16 + lr;
      #pragma unroll
      for (int j = 0; j < 4; ++j) {
        int rw = lg * 4 + j;
        int idx = rw * H_ + ((((coln >> 3) ^ (rw & 7))) << 3) + (coln & 7);
        htA[w][idx] = cvt1_bf16(fmaxf(aA[nt][j], 0.f));
        htC[w][idx] = cvt1_bf16(fmaxf(aC[nt][j], 0.f));
      }
    }
    // layer 2, both branches (wave-local ds round-trip, no barrier)
    short8 a2A[2], a2C[2];
    #pragma unroll
    for (int ks = 0; ks < 2; ++ks) {
      int c = ks * 4 + lg;
      a2A[ks] = *(const short8*)(&htA[w][lr * H_ + ((c ^ key) << 3)]);
      a2C[ks] = *(const short8*)(&htC[w][lr * H_ + ((c ^ key) << 3)]);
    }
    f32x4 cA[4], cC[4];
    #pragma unroll
    for (int nt = 0; nt < 4; ++nt) {
      cA[nt] = f32x4{b2A[nt], b2A[nt], b2A[nt], b2A[nt]};
      cC[nt] = f32x4{b2C[nt], b2C[nt], b2C[nt], b2C[nt]};
    }
    #pragma unroll
    for (int ks = 0; ks < 2; ++ks) {
      #pragma unroll
      for (int nt = 0; nt < 4; ++nt) {
        int n = nt * 16 + lr;
        cA[nt] = mfma16(a2A[ks], getW2(0, n, ks), cA[nt]);
        cC[nt] = mfma16(a2C[ks], getW2(1, n, ks), cC[nt]);
      }
    }
    #pragma unroll
    for (int nt = 0; nt < 4; ++nt) {
      int coln = nt * 16 + lr;
      #pragma unroll
      for (int j = 0; j < 4; ++j) {
        int rw = lg * 4 + j;
        int idx = rw * H_ + ((((coln >> 3) ^ (rw & 7))) << 3) + (coln & 7);
        htA[w][idx] = cvt1_bf16(fmaxf(cA[nt][j], 0.f));
        htC[w][idx] = cvt1_bf16(fmaxf(cC[nt][j], 0.f));
      }
    }
    // de-swizzling copy-out, both branches: PLAIN row-major x
    {
      long rt = base + s * 64 + (long)w * 16;
      ushort* dpA = xout + (size_t)rt * H_;
      ushort* dpC = xout + (size_t)XELEMS + (size_t)rt * H_;
      #pragma unroll
      for (int i = 0; i < 2; ++i) {
        int id = l + i * 64;          // 128 chunks of 16B
        int rr = id >> 3, cc = id & 7;
        uint4 vA = *(const uint4*)(&htA[w][rr * H_ + ((cc ^ (rr & 7)) << 3)]);
        *(uint4*)(dpA + rr * H_ + (cc << 3)) = vA;
        uint4 vC = *(const uint4*)(&htC[w][rr * H_ + ((cc ^ (rr & 7)) << 3)]);
        *(uint4*)(dpC + rr * H_ + (cc << 3)) = vC;
      }
    }
  };

  // 4-tile pipeline, obs double-buffered one compute ahead (named bufs, rule #20)
  float4 bufA[8], bufB[8];
  ldobs(0, bufA);
  ldobs(1, bufB);
  compute(0, bufA);
  ldobs(2, bufA);
  compute(1, bufB);
  ldobs(3, bufB);
  compute(2, bufA);
  compute(3, bufB);
}

// ---------------- phase 2: GRU scan, short-chain schedule (R8 structure) --------------
__global__ __launch_bounds__(256, 1) void scan_kernel(
    const ushort* __restrict__ wts,     // ws + WBASE region
    const ushort* __restrict__ xin,     // ws x region (load-only view)
    ushort* __restrict__ hist,          // ws x region (store-only view; t-disjoint)
    const float* __restrict__ dones,
    const float* __restrict__ astate, const float* __restrict__ cstate,
    const float* __restrict__ abih, const float* __restrict__ abhh,
    const float* __restrict__ cbih, const float* __restrict__ cbhh,
    float* __restrict__ out) {
  __shared__ __align__(16) ushort hbuf[2][16 * H_];  // h^T tiles, 16B-unit swizzled
  __shared__ __align__(8)  ushort dl16[T_ * 16];     // done flags, 16KB
  const int tid = threadIdx.x;
  const int l = tid & 63, w = tid >> 6;
  const int lr = l & 15, lg = l >> 4;
  const int grp = blockIdx.x & 1;
  const int b0 = (blockIdx.x >> 1) * 16;

  const ushort* wb = wts + grp * WBR;
  const ushort* xp = xin + (size_t)grp * XELEMS;
  ushort* hp = hist + (size_t)grp * XELEMS;
  const float* bihp = grp ? cbih : abih;
  const float* bhhp = grp ? cbhh : abhh;
  const float* st   = grp ? cstate : astate;

  // dones -> LDS flags
  #pragma unroll
  for (int i = 0; i < 8; ++i) {
    int s = tid + i * 256;
    int t = s >> 2, p = s & 3;
    float4 v = *(const float4*)(dones + (size_t)t * B_ + b0 + p * 4);
    uint lo = (v.x != 0.f ? 1u : 0u) | ((v.y != 0.f ? 1u : 0u) << 16);
    uint hi = (v.z != 0.f ? 1u : 0u) | ((v.w != 0.f ? 1u : 0u) << 16);
    *(uint2*)(&dl16[t * 16 + p * 4]) = uint2{lo, hi};
  }

  short8 ihW[3][2], hhW[3][2];
  #pragma unroll
  for (int g = 0; g < 3; ++g) {
    int n = g * 64 + w * 16 + lr;
    #pragma unroll
    for (int ks = 0; ks < 2; ++ks) {
      ihW[g][ks] = *(const short8*)(wb + WIHOFF + n * H_ + ks * 32 + lg * 8);
      hhW[g][ks] = *(const short8*)(wb + WHHOFF + n * H_ + ks * 32 + lg * 8);
    }
  }

  const int o4 = w * 16 + lg * 4;
  f32x4 bs0, bs1, binv, bhnv;
  {
    float4 a0 = *(const float4*)(bihp + o4),       h0v = *(const float4*)(bhhp + o4);
    float4 a1 = *(const float4*)(bihp + 64 + o4),  h1v = *(const float4*)(bhhp + 64 + o4);
    float4 a2 = *(const float4*)(bihp + 128 + o4), h2v = *(const float4*)(bhhp + 128 + o4);
    bs0[0]=S1_*(a0.x+h0v.x); bs0[1]=S1_*(a0.y+h0v.y); bs0[2]=S1_*(a0.z+h0v.z); bs0[3]=S1_*(a0.w+h0v.w);
    bs1[0]=S1_*(a1.x+h1v.x); bs1[1]=S1_*(a1.y+h1v.y); bs1[2]=S1_*(a1.z+h1v.z); bs1[3]=S1_*(a1.w+h1v.w);
    binv[0]=S2_*a2.x; binv[1]=S2_*a2.y; binv[2]=S2_*a2.z; binv[3]=S2_*a2.w;
    bhnv[0]=S2_*h2v.x; bhnv[1]=S2_*h2v.y; bhnv[2]=S2_*h2v.z; bhnv[3]=S2_*h2v.w;
  }

  const int myW = lr * H_ + (((w * 2 + (lg >> 1)) ^ (lr & 7)) << 3) + (lg & 1) * 4;
  const int rdA = lr * H_ + (((0 + lg) ^ (lr & 7)) << 3);
  const int rdB = lr * H_ + (((4 + lg) ^ (lr & 7)) << 3);

  float h_old[4];
  {
    float4 h0v = *(const float4*)(st + (size_t)(b0 + lr) * H_ + o4);
    bool rs0 = (dones[b0 + lr] != 0.f);
    h_old[0] = rs0 ? 0.f : h0v.x; h_old[1] = rs0 ? 0.f : h0v.y;
    h_old[2] = rs0 ? 0.f : h0v.z; h_old[3] = rs0 ? 0.f : h0v.w;
    uint2 hv;
    hv.x = cvt_pk_bf16(h_old[0], h_old[1]);
    hv.y = cvt_pk_bf16(h_old[2], h_old[3]);
    *(uint2*)(&hbuf[0][myW]) = hv;
  }

  __syncthreads();

  auto loadx = [&](int t, short8 (&f)[2]) {
    const ushort* p = xp + ((size_t)t * B_ + b0 + lr) * H_;
    f[0] = *(const short8*)(p + lg * 8);
    f[1] = *(const short8*)(p + 32 + lg * 8);
  };

  short8 buf0[2], buf1[2], buf2[2], buf3[2];
  loadx(0, buf0); loadx(1, buf1); loadx(2, buf2); loadx(3, buf3);

  // pre[g] = bias + ih·x for the step about to run (x-side, h-independent)
  f32x4 preA[3], preB[3];
  auto cpre = [&](short8 (&xb)[2], f32x4 (&pre)[3]) {
    pre[0] = bs0;  pre[1] = bs1;  pre[2] = binv;
    pre[0] = mfma16(ihW[0][0], xb[0], pre[0]); pre[0] = mfma16(ihW[0][1], xb[1], pre[0]);
    pre[1] = mfma16(ihW[1][0], xb[0], pre[1]); pre[1] = mfma16(ihW[1][1], xb[1], pre[1]);
    pre[2] = mfma16(ihW[2][0], xb[0], pre[2]); pre[2] = mfma16(ihW[2][1], xb[1], pre[2]);
  };
  cpre(buf0, preA);

  int cur = 0;

  auto dostep = [&](int t, short8 (&xcur)[2], short8 (&xnext)[2],
                    f32x4 (&preU)[3], f32x4 (&preN)[3]) {
    short8 hf0 = *(const short8*)(&hbuf[cur][rdA]);
    short8 hf1 = *(const short8*)(&hbuf[cur][rdB]);
    int tn = t + 1;
    ushort dn = dl16[((tn < T_) ? tn : 0) * 16 + lr];
    bool rs = (tn < T_) && (dn != 0);

    // critical path: 2 chained hh-MFMAs per gate (C = bias + ih·x, precomputed)
    f32x4 S0 = preU[0], S1 = preU[1], Gh = bhnv;
    S0 = mfma16(hhW[0][0], hf0, S0); S0 = mfma16(hhW[0][1], hf1, S0);
    S1 = mfma16(hhW[1][0], hf0, S1); S1 = mfma16(hhW[1][1], hf1, S1);
    Gh = mfma16(hhW[2][0], hf0, Gh); Gh = mfma16(hhW[2][1], hf1, Gh);

    // latency shadow: x-side MFMAs for t+1 and the t+4 prefetch
    cpre(xnext, preN);
    int tp = (t + 4 < T_) ? t + 4 : T_ - 1;
    loadx(tp, xcur);

    float hn[4];
    #pragma unroll
    for (int j = 0; j < 4; ++j) {
      float rr = __builtin_amdgcn_rcpf(1.f + __builtin_amdgcn_exp2f(S0[j]));
      float zz = __builtin_amdgcn_rcpf(1.f + __builtin_amdgcn_exp2f(S1[j]));
      float sn = fmaf(rr, Gh[j], preU[2][j]);
      float qq = __builtin_amdgcn_rcpf(1.f + __builtin_amdgcn_exp2f(sn));
      float nn = fmaf(2.f, qq, -1.f);
      hn[j] = fmaf(zz, h_old[j] - nn, nn);
    }
    uint2 hv;
    hv.x = cvt_pk_bf16(hn[0], hn[1]);
    hv.y = cvt_pk_bf16(hn[2], hn[3]);
    *(uint2*)(hp + ((size_t)t * B_ + b0 + lr) * H_ + o4) = hv;   // history (pre-reset)
    uint2 hz;
    hz.x = rs ? 0u : hv.x;
    hz.y = rs ? 0u : hv.y;
    h_old[0] = rs ? 0.f : hn[0]; h_old[1] = rs ? 0.f : hn[1];
    h_old[2] = rs ? 0.f : hn[2]; h_old[3] = rs ? 0.f : hn[3];
    int nxt = cur ^ 1;
    *(uint2*)(&hbuf[nxt][myW]) = hz;
    asm volatile("s_waitcnt lgkmcnt(0)" ::: "memory");
    __builtin_amdgcn_s_barrier();
    cur = nxt;
  };

  for (int it = 0; it < T_ / 4; ++it) {
    dostep(4 * it,     buf0, buf1, preA, preB);
    dostep(4 * it + 1, buf1, buf2, preB, preA);
    dostep(4 * it + 2, buf2, buf3, preA, preB);
    dostep(4 * it + 3, buf3, buf0, preB, preA);
  }

  // final states (fp32, post step 511; no reset applied on last step)
  float4 fs = {h_old[0], h_old[1], h_old[2], h_old[3]};
  *(float4*)(out + SOFF_ + (size_t)grp * (B_ * H_) + (size_t)(b0 + lr) * H_ + o4) = fs;
}

// ---------------- phase 3: heads (logits + values), LDS-staged coalesced stores -------
__global__ __launch_bounds__(256) void head_kernel(
    const ushort* __restrict__ ws,
    const float* __restrict__ abl, const float* __restrict__ cbv,
    float* __restrict__ out) {
  __shared__ float ltile[4][16 * A_];
  const int tid = threadIdx.x;
  const int l = tid & 63, w = tid >> 6;
  const int lr = l & 15, lg = l >> 4;
  const long r0 = (long)blockIdx.x * 64 + w * 16;
  const f32x4 fzero = {0.f, 0.f, 0.f, 0.f};

  const ushort* hA = ws + r0 * H_;
  const ushort* hC = ws + XELEMS + r0 * H_;
  short8 aA[2], aC[2];
  #pragma unroll
  for (int ks = 0; ks < 2; ++ks) {
    aA[ks] = *(const short8*)(hA + lr * H_ + ks * 32 + lg * 8);
    aC[ks] = *(const short8*)(hC + lr * H_ + ks * 32 + lg * 8);
  }
  const ushort* wbA = ws + WBASE + WHDOFF;
  const ushort* wbC = ws + WBASE + WBR + WHDOFF;
  f32x4 acc[2];
  acc[0] = fzero; acc[1] = fzero;
  #pragma unroll
  for (int nt = 0; nt < 2; ++nt) {
    int n = nt * 16 + lr;
    #pragma unroll
    for (int ks = 0; ks < 2; ++ks) {
      short8 b = *(const short8*)(wbA + n * H_ + ks * 32 + lg * 8);
      acc[nt] = mfma16(aA[ks], b, acc[nt]);
    }
  }
  f32x4 vacc = fzero;
  {
    int n = lr;
    #pragma unroll
    for (int ks = 0; ks < 2; ++ks) {
      short8 b = *(const short8*)(wbC + n * H_ + ks * 32 + lg * 8);
      vacc = mfma16(aC[ks], b, vacc);
    }
  }
  #pragma unroll
  for (int nt = 0; nt < 2; ++nt) {
    int n = nt * 16 + lr;
    if (n < A_) {
      float bias = abl[n];
      #pragma unroll
      for (int j = 0; j < 4; ++j)
        ltile[w][(lg * 4 + j) * A_ + n] = acc[nt][j] + bias;
    }
  }
  asm volatile("s_waitcnt lgkmcnt(0)" ::: "memory");
  #pragma unroll
  for (int i = 0; i < 5; ++i) {
    int idx = l + i * 64;
    if (idx < 16 * A_)
      out[r0 * A_ + idx] = ltile[w][idx];
  }
  if (lr == 0) {
    float bias = cbv[0];
    #pragma unroll
    for (int j = 0; j < 4; ++j)
      out[VOFF_ + r0 + lg * 4 + j] = vacc[j] + bias;
  }
}

extern "C" void kernel_launch(void* const* d_in, const int* in_sizes, int n_in,
                              void* d_out, int out_size, void* d_ws, size_t ws_size,
                              hipStream_t stream) {
  const float* obs    = (const float*)d_in[0];
  const float* dones  = (const float*)d_in[1];
  const float* astate = (const float*)d_in[2];
  const float* cstate = (const float*)d_in[3];
  const float* aW1  = (const float*)d_in[4];
  const float* ab1  = (const float*)d_in[5];
  const float* aW2  = (const float*)d_in[6];
  const float* ab2  = (const float*)d_in[7];
  const float* aWih = (const float*)d_in[8];
  const float* aWhh = (const float*)d_in[9];
  const float* abih = (const float*)d_in[10];
  const float* abhh = (const float*)d_in[11];
  const float* aWl  = (const float*)d_in[12];
  const float* abl  = (const float*)d_in[13];
  const float* cW1  = (const float*)d_in[14];
  const float* cb1  = (const float*)d_in[15];
  const float* cW2  = (const float*)d_in[16];
  const float* cb2  = (const float*)d_in[17];
  const float* cWih = (const float*)d_in[18];
  const float* cWhh = (const float*)d_in[19];
  const float* cbih = (const float*)d_in[20];
  const float* cbhh = (const float*)d_in[21];
  const float* cWv  = (const float*)d_in[22];
  const float* cbv  = (const float*)d_in[23];
  ushort* ws = (ushort*)d_ws;
  float* out = (float*)d_out;

  const size_t need = ((size_t)2 * XELEMS + 2 * WBR) * 2;
  if (ws_size < need) {
    hipMemsetAsync(d_out, 0x7F, 16, stream);
    return;
  }

  hipLaunchKernelGGL(prep_kernel, dim3(304), dim3(256), 0, stream,
                     aW1, aW2, aWih, aWhh, aWl, cW1, cW2, cWih, cWhh, cWv, ws);
  hipLaunchKernelGGL(mlp_kernel, dim3(TB_ / 256), dim3(256), 0, stream,
                     obs, ws, ab1, ab2, cb1, cb2, ws);
  hipLaunchKernelGGL(scan_kernel, dim3(128), dim3(256), 0, stream,
                     ws + WBASE, ws, ws, dones, astate, cstate,
                     abih, abhh, cbih, cbhh, out);
  hipLaunchKernelGGL(head_kernel, dim3(TB_ / 64), dim3(256), 0, stream,
                     ws, abl, cbv, out);
}